// Round 14
// baseline (787.442 us; speedup 1.0000x reference)
//
#include <hip/hip_runtime.h>

// ---------------------------------------------------------------------------
// GCNPredictor: 3x (bf16 MFMA GEMM -> sliced bf16 pull-gather+BNstats -> BN
// folded into next GEMM) + head.  N=50000, E=800000, D=H=128.
//
// Round-14: resubmission of round-13 (GPU acquisition timeout; never ran).
// Gather is L2-miss-path bound (82MB fabric fill/dispatch). Fix: feature-
// slice the gather 8 ways, slice=blockIdx&7 -> XCD-pinned via round-robin
// dispatch; per-XCD slice working set = N*32B = 1.6MB -> L2-resident.
// Slice = 16 bf16 cols (32B/row). Edge meta packed to 4B (src16|coef_bf16),
// nontemporal loads; out stores nontemporal (protect resident slice).
//
// Workspace:
//   hw_b  [N*128] u16     GEMM output (message rows, bf16)
//   hbuf_b[N*128] u16     aggregation output (pre-BN, bf16)
//   dinv  [N] f32         rsqrt(weighted degree incl self-loop)
//   stats3[3][64*256] f32 per-layer 64-replica col sum/sumsq
//   ab    [3*256] f32     per-layer folded BN affine A,B
//   wcells[3][4096] u64   pre-packed swizzled bf16 W
//   cnt/ptr/bsum/rank     CSC build (int)
//   emeta [E] int2        CSC: (src idx, w bits)  [build only]
//   epack [E] u32         CSC: src16<<16 | coef_bf16  [gather]
// ---------------------------------------------------------------------------

typedef unsigned short u16;
typedef unsigned int u32;
typedef unsigned long long u64;
typedef short bf16x8 __attribute__((ext_vector_type(8)));
typedef float f32x4 __attribute__((ext_vector_type(4)));

#define NREP 64   // stats replicas per layer

__device__ inline float bf2f(u16 u) { return __uint_as_float(((u32)u) << 16); }
__device__ inline u16 f2bf(float f) {          // RTNE, finite inputs
  u32 u = __float_as_uint(f);
  return (u16)((u + 0x7FFFu + ((u >> 16) & 1u)) >> 16);
}

// ---------------- CSC build ------------------------------------------------
__global__ __launch_bounds__(256) void k_zero_cnt(int* cnt, int n) {
  int i = blockIdx.x * 256 + threadIdx.x;
  if (i < n) cnt[i] = 0;
}

__global__ __launch_bounds__(256) void k_count_rank(const int* __restrict__ col,
                                                    int* __restrict__ cnt,
                                                    int* __restrict__ rank, int e) {
  int i = blockIdx.x * 256 + threadIdx.x;
  if (i < e) rank[i] = atomicAdd(&cnt[col[i]], 1);
}

__global__ __launch_bounds__(256) void k_scan1(const int* __restrict__ cnt,
                                               int* __restrict__ ptr,
                                               int* __restrict__ bsum, int n) {
  __shared__ int sh[256];
  int t = threadIdx.x;
  int i = blockIdx.x * 256 + t;
  int v = (i < n) ? cnt[i] : 0;
  sh[t] = v;
  __syncthreads();
  for (int d = 1; d < 256; d <<= 1) {
    int u = (t >= d) ? sh[t - d] : 0;
    __syncthreads();
    sh[t] += u;
    __syncthreads();
  }
  if (i < n) ptr[i] = sh[t] - v;
  if (t == 255) bsum[blockIdx.x] = sh[255];
}

__global__ __launch_bounds__(256) void k_scan2(int* __restrict__ bsum, int nb) {
  __shared__ int sh[256];
  int t = threadIdx.x;
  int v = (t < nb) ? bsum[t] : 0;
  sh[t] = v;
  __syncthreads();
  for (int d = 1; d < 256; d <<= 1) {
    int u = (t >= d) ? sh[t - d] : 0;
    __syncthreads();
    sh[t] += u;
    __syncthreads();
  }
  if (t < nb) bsum[t] = sh[t] - v;
}

__global__ __launch_bounds__(256) void k_scan3(int* __restrict__ ptr,
                                               const int* __restrict__ bsum,
                                               int n, int e) {
  int i = blockIdx.x * 256 + threadIdx.x;
  if (i < n) ptr[i] += bsum[blockIdx.x];
  if (i == 0) ptr[n] = e;
}

// Fill CSC: slot = ptr[col]+rank. Store (src index, raw w fp32).
__global__ __launch_bounds__(256) void k_fill(const int* __restrict__ row,
                                              const int* __restrict__ col,
                                              const float* __restrict__ w,
                                              const int* __restrict__ ptr,
                                              const int* __restrict__ rank,
                                              int2* __restrict__ emeta, int e) {
  int i = blockIdx.x * 256 + threadIdx.x;
  if (i < e) {
    int pos = ptr[col[i]] + rank[i];
    emeta[pos] = make_int2(row[i], __float_as_int(w[i]));
  }
}

__global__ __launch_bounds__(256) void k_deg_dinv(const int* __restrict__ ptr,
                                                  const int2* __restrict__ emeta,
                                                  float* __restrict__ dinv, int n) {
  int i = blockIdx.x * 256 + threadIdx.x;
  if (i >= n) return;
  int j = ptr[i], end = ptr[i + 1];
  float d = 1.0f;
  for (; j < end; ++j) d += __int_as_float(emeta[j].y);
  dinv[i] = rsqrtf(d);
}

// coef = dinv[src]*w*dinv[dst] (fp32), packed: src16<<16 | bf16(coef).
__global__ __launch_bounds__(256) void k_coef(const int* __restrict__ ptr,
                                              const int2* __restrict__ emeta,
                                              const float* __restrict__ dinv,
                                              u32* __restrict__ epack, int n) {
  int i = blockIdx.x * 256 + threadIdx.x;
  if (i >= n) return;
  float dc = dinv[i];
  int j = ptr[i], end = ptr[i + 1];
  for (; j < end; ++j) {
    int2 m = emeta[j];
    float c = dinv[m.x] * __int_as_float(m.y) * dc;
    epack[j] = ((u32)m.x << 16) | (u32)f2bf(c);
  }
}

// ---------------- W pre-pack: fp32 row-major -> swizzled bf16 u64 cells ----
__global__ __launch_bounds__(256) void k_wpack(const float* __restrict__ W0,
                                               const float* __restrict__ W1,
                                               const float* __restrict__ W2,
                                               u64* __restrict__ cells) {
  const float* W = (blockIdx.x == 0) ? W0 : (blockIdx.x == 1) ? W1 : W2;
  u64* out = cells + (size_t)blockIdx.x * 4096;
  int t = threadIdx.x;
#pragma unroll
  for (int i = 0; i < 16; ++i) {
    int cell = t + 256 * i;        // 0..4095
    int col = cell >> 5;
    int k4 = cell & 31;
    int k = k4 * 4;
    u64 c = (u64)f2bf(W[(size_t)(k + 0) * 128 + col]) |
            ((u64)f2bf(W[(size_t)(k + 1) * 128 + col]) << 16) |
            ((u64)f2bf(W[(size_t)(k + 2) * 128 + col]) << 32) |
            ((u64)f2bf(W[(size_t)(k + 3) * 128 + col]) << 48);
    out[col * 32 + (k4 ^ (col & 15))] = c;
  }
}

// ---------------- bf16 MFMA GEMM -------------------------------------------
// C[n x 128](bf16) = act(A)[n x 128] * W[128 x 128].
// act = relu(v*A+B) with (A,B)=ab (prev layer's folded BN affine), or
// identity for layer 0. Blocks 0..15 zero this layer's 64-replica stats.
// W arrives pre-packed/swizzled; staging is a pure 32KB copy. LDS cells:
// 8B (4 bf16 along k) at [r*32 + (k4 ^ (r&15))]. C/D: col=lane&15,
// row=(lane>>4)*4+reg (m89-verified).
__global__ __launch_bounds__(256) void k_gemm(const void* __restrict__ Ain,
                                              int a_is_f32,
                                              const u64* __restrict__ Wc,
                                              u16* __restrict__ C,
                                              const float* __restrict__ ab,
                                              float* __restrict__ Szero,
                                              int n) {
  __shared__ u64 As64[128 * 32];   // 32 KB
  __shared__ u64 Ws64[128 * 32];   // 32 KB
  __shared__ float absh[256];      // folded BN affine A,B
  int t = threadIdx.x;
  if (blockIdx.x < 16) {           // zero this layer's 64-replica stats
#pragma unroll
    for (int i = 0; i < 4; ++i)
      Szero[blockIdx.x * 1024 + t + 256 * i] = 0.f;
  }
  {  // stage pre-packed W: pure copy, 16B vectors
    const ulonglong2* src = (const ulonglong2*)Wc;
    ulonglong2* dst = (ulonglong2*)Ws64;
#pragma unroll
    for (int i = 0; i < 8; ++i) dst[t + 256 * i] = src[t + 256 * i];
  }
  if (ab) {
    if (t < 128) {
      absh[t] = ab[t];
      absh[128 + t] = ab[128 + t];
    }
  }

  int row0 = blockIdx.x * 128;
  int nr = min(128, n - row0);

  if (a_is_f32) {                  // layer 0: fp32 input, no affine
    const float4* src = (const float4*)((const float*)Ain + (size_t)row0 * 128);
#pragma unroll
    for (int i = 0; i < 16; ++i) {
      int idx = t + 256 * i;       // float4 id within tile
      int r = idx >> 5;
      int j4 = idx & 31;           // cell k4 = j4
      float4 v = (r < nr) ? src[idx] : make_float4(0.f, 0.f, 0.f, 0.f);
      u64 cell = (u64)f2bf(v.x) | ((u64)f2bf(v.y) << 16) |
                 ((u64)f2bf(v.z) << 32) | ((u64)f2bf(v.w) << 48);
      As64[r * 32 + (j4 ^ (r & 15))] = cell;
    }
  } else {                         // bf16 input (+ optional affine+relu)
    const u16* A = (const u16*)Ain;
    __syncthreads();               // absh visible
#pragma unroll
    for (int i = 0; i < 8; ++i) {
      int idx = t + 256 * i;       // 16B chunk id
      int r = idx >> 4;
      int c8 = idx & 15;           // 8-bf16 chunk
      u64 lo = 0, hi = 0;
      if (r < nr) {
        const u64* srcq = (const u64*)(A + ((size_t)(row0 + r)) * 128 + c8 * 8);
        lo = srcq[0]; hi = srcq[1];
        if (ab) {
          u64 nl = 0, nh = 0;
#pragma unroll
          for (int j = 0; j < 4; ++j) {
            int c = c8 * 8 + j;
            float f = fmaxf(fmaf(bf2f((u16)(lo >> (16 * j))), absh[c], absh[128 + c]), 0.f);
            nl |= ((u64)f2bf(f)) << (16 * j);
            int c2 = c + 4;
            float f2 = fmaxf(fmaf(bf2f((u16)(hi >> (16 * j))), absh[c2], absh[128 + c2]), 0.f);
            nh |= ((u64)f2bf(f2)) << (16 * j);
          }
          lo = nl; hi = nh;
        }
      }
      As64[r * 32 + ((c8 * 2) ^ (r & 15))] = lo;
      As64[r * 32 + ((c8 * 2 + 1) ^ (r & 15))] = hi;
    }
  }
  __syncthreads();

  int w = t >> 6, l = t & 63;
  int lr = l & 15, kg = l >> 4;
  int rA0 = w * 32 + lr, rA1 = rA0 + 16;   // rA&15 == lr
  f32x4 acc[2][8];
#pragma unroll
  for (int m = 0; m < 2; ++m)
#pragma unroll
    for (int nf = 0; nf < 8; ++nf) acc[m][nf] = (f32x4){0.f, 0.f, 0.f, 0.f};

  union Frag { u64 q[2]; bf16x8 v; };
#pragma unroll
  for (int ks = 0; ks < 4; ++ks) {
    int kb = ks * 8 + kg;
    Frag a0, a1;
    a0.q[0] = As64[rA0 * 32 + (kb ^ lr)];
    a0.q[1] = As64[rA0 * 32 + ((kb + 4) ^ lr)];
    a1.q[0] = As64[rA1 * 32 + (kb ^ lr)];
    a1.q[1] = As64[rA1 * 32 + ((kb + 4) ^ lr)];
#pragma unroll
    for (int nf = 0; nf < 8; ++nf) {
      Frag b;
      b.q[0] = Ws64[(nf * 16 + lr) * 32 + (kb ^ lr)];
      b.q[1] = Ws64[(nf * 16 + lr) * 32 + ((kb + 4) ^ lr)];
      acc[0][nf] = __builtin_amdgcn_mfma_f32_16x16x32_bf16(a0.v, b.v, acc[0][nf], 0, 0, 0);
      acc[1][nf] = __builtin_amdgcn_mfma_f32_16x16x32_bf16(a1.v, b.v, acc[1][nf], 0, 0, 0);
    }
  }
#pragma unroll
  for (int m = 0; m < 2; ++m)
#pragma unroll
    for (int nf = 0; nf < 8; ++nf)
#pragma unroll
      for (int j = 0; j < 4; ++j) {
        int gr = row0 + w * 32 + m * 16 + kg * 4 + j;
        if (gr < n) C[(size_t)gr * 128 + nf * 16 + lr] = f2bf(acc[m][nf][j]);
      }
}

// ---------------- sliced bf16 pull-gather + fused BN stats -----------------
// Grid = tiles*8; slice = blockIdx&7 (XCD-pinned by round-robin dispatch).
// Slice = 16 bf16 cols = 32B/row; per-XCD working set 1.6MB -> L2-resident.
// Wave = 1 node: 8 edge-subs x 8 col-u32 lanes; butterfly over edge-subs.
// epack nontemporal (stream, don't evict slice); out stores nontemporal.
__global__ __launch_bounds__(256) void k_gather(const u16* __restrict__ hw,
                                                const int* __restrict__ ptr,
                                                const u32* __restrict__ epack,
                                                const float* __restrict__ dinv,
                                                u16* __restrict__ out,
                                                float* __restrict__ stats, int n) {
  int slice = blockIdx.x & 7;
  int tile = blockIdx.x >> 3;
  int w = threadIdx.x >> 6;
  int lane = threadIdx.x & 63;
  int es = lane >> 3;                    // edge-sub 0..7
  int cu = lane & 7;                     // u32-col within slice
  int colb = slice * 32 + cu * 4;        // byte offset within 256B row
  const char* hwb = (const char*)hw;
  float sx = 0.f, sy = 0.f, sxx = 0.f, syy = 0.f;
#pragma unroll
  for (int it = 0; it < 4; ++it) {
    int node = tile * 16 + it * 4 + w;
    if (node < n) {
      float di = dinv[node];
      u32 su = *(const u32*)(hwb + ((size_t)node << 8) + colb);
      float ax = 0.f, ay = 0.f;
      if (es == 0) {
        ax = __uint_as_float(su << 16) * di * di;
        ay = __uint_as_float(su & 0xFFFF0000u) * di * di;
      }
      int end = ptr[node + 1];
      for (int j = ptr[node] + es; j < end; j += 8) {
        u32 m = __builtin_nontemporal_load(epack + j);
        float c = __uint_as_float(m << 16);          // bf16 coef -> f32
        u32 v = *(const u32*)(hwb + ((m & 0xFFFF0000u) >> 8) + colb);
        ax = fmaf(__uint_as_float(v << 16), c, ax);
        ay = fmaf(__uint_as_float(v & 0xFFFF0000u), c, ay);
      }
      ax += __shfl_xor(ax, 8);  ay += __shfl_xor(ay, 8);
      ax += __shfl_xor(ax, 16); ay += __shfl_xor(ay, 16);
      ax += __shfl_xor(ax, 32); ay += __shfl_xor(ay, 32);
      if (es == 0) {
        u32 o = (u32)f2bf(ax) | ((u32)f2bf(ay) << 16);
        __builtin_nontemporal_store(o,
            (u32*)((char*)out + ((size_t)node << 8) + colb));
      }
      sx += ax; sy += ay;
      sxx = fmaf(ax, ax, sxx); syy = fmaf(ay, ay, syy);
    }
  }
  __shared__ float4 red[32];
  if (es == 0) red[w * 8 + cu] = make_float4(sx, sy, sxx, syy);
  __syncthreads();
  if (threadIdx.x < 8) {
    int t = threadIdx.x;
    float4 a = red[t], b = red[8 + t], c4 = red[16 + t], d = red[24 + t];
    float* S = stats + (tile & (NREP - 1)) * 256;
    int c0 = (slice * 8 + t) * 2;
    unsafeAtomicAdd(&S[c0],           a.x + b.x + c4.x + d.x);
    unsafeAtomicAdd(&S[c0 + 1],       a.y + b.y + c4.y + d.y);
    unsafeAtomicAdd(&S[128 + c0],     a.z + b.z + c4.z + d.z);
    unsafeAtomicAdd(&S[128 + c0 + 1], a.w + b.w + c4.w + d.w);
  }
}

// ---------------- BN finalize: reduce replicas -> folded affine ------------
__global__ __launch_bounds__(128) void k_bn_finalize(const float* __restrict__ S,
                                                     const float* __restrict__ g,
                                                     const float* __restrict__ be,
                                                     float* __restrict__ ab, int n) {
  int c = threadIdx.x;
  float s = 0.f, ss = 0.f;
#pragma unroll 8
  for (int r = 0; r < NREP; ++r) {
    s += S[r * 256 + c];
    ss += S[r * 256 + 128 + c];
  }
  float inv_n = 1.0f / (float)n;
  float mu = s * inv_n;
  float var = ss * inv_n - mu * mu;
  float istd = rsqrtf(var + 1e-5f);
  float A = g[c] * istd;
  ab[c] = A;
  ab[128 + c] = fmaf(-mu, A, be[c]);
}

// ---------------- head -----------------------------------------------------
__global__ __launch_bounds__(256) void k_head(const u16* __restrict__ h,
                                              const float* __restrict__ ab,
                                              const float* __restrict__ Wh,
                                              const float* __restrict__ bh,
                                              const float* __restrict__ Wa,
                                              const float* __restrict__ ba,
                                              const float* __restrict__ Wz,
                                              const float* __restrict__ bz,
                                              float* __restrict__ out) {
  __shared__ float hrow[256];
  __shared__ float red[256];
  int t = threadIdx.x;
  {
    int c = t & 127;
    hrow[t] = fmaxf(fmaf(bf2f(h[t]), ab[c], ab[128 + c]), 0.f);
  }
  __syncthreads();
  int j = t & 127, r = t >> 7;
  float acc = bh[j];
  for (int k = 0; k < 128; ++k)
    acc = fmaf(hrow[r * 128 + k], Wh[k * 128 + j], acc);
  float hv = fmaxf(acc, 0.f);
  float wv = (r == 0) ? Wa[j] : Wz[j];
  red[t] = hv * wv;
  __syncthreads();
  for (int s = 64; s >= 1; s >>= 1) {
    if (j < s) red[t] += red[t + s];
    __syncthreads();
  }
  if (t == 0) out[0] = red[0] + ba[0];
  if (t == 128) out[1] = red[128] + bz[0];
}

extern "C" void kernel_launch(void* const* d_in, const int* in_sizes, int n_in,
                              void* d_out, int out_size, void* d_ws, size_t ws_size,
                              hipStream_t stream) {
  const float* x  = (const float*)d_in[0];
  const int*   ei = (const int*)d_in[1];
  const float* ew = (const float*)d_in[2];
  const float* W[3]  = {(const float*)d_in[3], (const float*)d_in[5], (const float*)d_in[7]};
  // b1/b2/b3 cancel inside BatchNorm -> skipped.
  const float* g[3]  = {(const float*)d_in[9],  (const float*)d_in[11], (const float*)d_in[13]};
  const float* be[3] = {(const float*)d_in[10], (const float*)d_in[12], (const float*)d_in[14]};
  const float* Wh = (const float*)d_in[15];
  const float* bh = (const float*)d_in[16];
  const float* Wa = (const float*)d_in[17];
  const float* ba = (const float*)d_in[18];
  const float* Wz = (const float*)d_in[19];
  const float* bz = (const float*)d_in[20];

  const int n = in_sizes[0] / 128;
  const int e = in_sizes[1] / 2;
  const int* row = ei;
  const int* col = ei + e;

  u16*   hw_b   = (u16*)d_ws;
  u16*   hbuf_b = hw_b + (size_t)n * 128;
  float* dinv   = (float*)(hbuf_b + (size_t)n * 128);
  float* stats3 = dinv + n;                 // 3 * NREP * 256
  float* ab     = stats3 + 3 * NREP * 256;  // 3 * 256
  u64*   wcells = (u64*)(ab + 3 * 256);     // 3 * 4096
  int*   cnt    = (int*)(wcells + 3 * 4096);
  int*   ptr    = cnt + n;
  int*   bsum   = ptr + n + 1;              // 256
  int*   rank   = bsum + 256;               // E
  u32*   epack  = (u32*)(rank + e);         // E
  uintptr_t pm  = ((uintptr_t)(epack + e) + 15) & ~(uintptr_t)15;
  int2*  emeta  = (int2*)pm;                // E

  const int nb_n = (n + 255) / 256;
  const int nb_e = (e + 255) / 256;

  k_zero_cnt<<<nb_n, 256, 0, stream>>>(cnt, n);
  k_count_rank<<<nb_e, 256, 0, stream>>>(col, cnt, rank, e);
  k_scan1<<<nb_n, 256, 0, stream>>>(cnt, ptr, bsum, n);
  k_scan2<<<1, 256, 0, stream>>>(bsum, nb_n);
  k_scan3<<<nb_n, 256, 0, stream>>>(ptr, bsum, n, e);
  k_fill<<<nb_e, 256, 0, stream>>>(row, col, ew, ptr, rank, emeta, e);
  k_deg_dinv<<<nb_n, 256, 0, stream>>>(ptr, emeta, dinv, n);
  k_coef<<<nb_n, 256, 0, stream>>>(ptr, emeta, dinv, epack, n);
  k_wpack<<<3, 256, 0, stream>>>(W[0], W[1], W[2], wcells);

  const int ntile = (n + 15) / 16;
  for (int l = 0; l < 3; ++l) {
    const void* hin = (l == 0) ? (const void*)x : (const void*)hbuf_b;
    const float* abp = (l == 0) ? nullptr : (ab + (l - 1) * 256);
    k_gemm<<<(n + 127) / 128, 256, 0, stream>>>(hin, (l == 0) ? 1 : 0,
                                                wcells + (size_t)l * 4096,
                                                hw_b, abp,
                                                stats3 + l * NREP * 256, n);
    k_gather<<<ntile * 8, 256, 0, stream>>>(hw_b, ptr, epack, dinv, hbuf_b,
                                            stats3 + l * NREP * 256, n);
    k_bn_finalize<<<1, 128, 0, stream>>>(stats3 + l * NREP * 256, g[l], be[l],
                                         ab + l * 256, n);
  }
  k_head<<<1, 256, 0, stream>>>(hbuf_b, ab + 2 * 256, Wh, bh, Wa, ba, Wz, bz,
                                (float*)d_out);
}

// Round 15
// 373.202 us; speedup vs baseline: 2.1100x; 2.1100x over previous
//
#include <hip/hip_runtime.h>

// ---------------------------------------------------------------------------
// GCNPredictor: 3x (bf16 MFMA GEMM -> bf16 pull-gather+BNstats -> BN folded
// into next GEMM) + head.  N=50000, E=800000, D=H=128.
//
// Round-15: revert round-14's sliced gather (XCD pinning via blockIdx&7 is
// invalid: FETCH 82->197MB, 190us). Back to round-12 full-row gather (at its
// ~41us fabric floor). New: edge meta = u32 (src16|coef_bf16) everywhere ->
// fill's random writes halved, gather meta stream halved; degree computed
// from bf16 w (error ~0.05%, absmax unchanged 3.9e-3 per round-14 evidence);
// cnt zeroed via hipMemsetAsync (launch removed).
//
// Workspace:
//   hw_b  [N*128] u16     GEMM output (message rows, bf16)
//   hbuf_b[N*128] u16     aggregation output (pre-BN, bf16)
//   dinv  [N] f32         rsqrt(weighted degree incl self-loop)
//   stats3[3][64*256] f32 per-layer 64-replica col sum/sumsq
//   ab    [3*256] f32     per-layer folded BN affine A,B
//   wcells[3][4096] u64   pre-packed swizzled bf16 W
//   cnt/ptr/bsum/rank     CSC build (int)
//   epack [E] u32         CSC: src16<<16 | bf16(w) -> src16<<16 | bf16(coef)
// ---------------------------------------------------------------------------

typedef unsigned short u16;
typedef unsigned int u32;
typedef unsigned long long u64;
typedef short bf16x8 __attribute__((ext_vector_type(8)));
typedef float f32x4 __attribute__((ext_vector_type(4)));

#define NREP 64   // stats replicas per layer

__device__ inline float bf2f(u16 u) { return __uint_as_float(((u32)u) << 16); }
__device__ inline u16 f2bf(float f) {          // RTNE, finite inputs
  u32 u = __float_as_uint(f);
  return (u16)((u + 0x7FFFu + ((u >> 16) & 1u)) >> 16);
}

// ---------------- CSC build ------------------------------------------------
__global__ __launch_bounds__(256) void k_count_rank(const int* __restrict__ col,
                                                    int* __restrict__ cnt,
                                                    int* __restrict__ rank, int e) {
  int i = blockIdx.x * 256 + threadIdx.x;
  if (i < e) rank[i] = atomicAdd(&cnt[col[i]], 1);
}

__global__ __launch_bounds__(256) void k_scan1(const int* __restrict__ cnt,
                                               int* __restrict__ ptr,
                                               int* __restrict__ bsum, int n) {
  __shared__ int sh[256];
  int t = threadIdx.x;
  int i = blockIdx.x * 256 + t;
  int v = (i < n) ? cnt[i] : 0;
  sh[t] = v;
  __syncthreads();
  for (int d = 1; d < 256; d <<= 1) {
    int u = (t >= d) ? sh[t - d] : 0;
    __syncthreads();
    sh[t] += u;
    __syncthreads();
  }
  if (i < n) ptr[i] = sh[t] - v;
  if (t == 255) bsum[blockIdx.x] = sh[255];
}

__global__ __launch_bounds__(256) void k_scan2(int* __restrict__ bsum, int nb) {
  __shared__ int sh[256];
  int t = threadIdx.x;
  int v = (t < nb) ? bsum[t] : 0;
  sh[t] = v;
  __syncthreads();
  for (int d = 1; d < 256; d <<= 1) {
    int u = (t >= d) ? sh[t - d] : 0;
    __syncthreads();
    sh[t] += u;
    __syncthreads();
  }
  if (t < nb) bsum[t] = sh[t] - v;
}

__global__ __launch_bounds__(256) void k_scan3(int* __restrict__ ptr,
                                               const int* __restrict__ bsum,
                                               int n, int e) {
  int i = blockIdx.x * 256 + threadIdx.x;
  if (i < n) ptr[i] += bsum[blockIdx.x];
  if (i == 0) ptr[n] = e;
}

// Fill CSC: slot = ptr[col]+rank. Store src16<<16 | bf16(w). 4B random write.
__global__ __launch_bounds__(256) void k_fill(const int* __restrict__ row,
                                              const int* __restrict__ col,
                                              const float* __restrict__ w,
                                              const int* __restrict__ ptr,
                                              const int* __restrict__ rank,
                                              u32* __restrict__ epack, int e) {
  int i = blockIdx.x * 256 + threadIdx.x;
  if (i < e) {
    int pos = ptr[col[i]] + rank[i];
    epack[pos] = ((u32)row[i] << 16) | (u32)f2bf(w[i]);
  }
}

// deg = 1 (self-loop) + sum of incoming bf16(w); fp32 accumulate.
__global__ __launch_bounds__(256) void k_deg_dinv(const int* __restrict__ ptr,
                                                  const u32* __restrict__ epack,
                                                  float* __restrict__ dinv, int n) {
  int i = blockIdx.x * 256 + threadIdx.x;
  if (i >= n) return;
  int j = ptr[i], end = ptr[i + 1];
  float d = 1.0f;
  for (; j < end; ++j) d += __uint_as_float(epack[j] << 16);
  dinv[i] = rsqrtf(d);
}

// coef = dinv[src]*w*dinv[dst]; rewrite low 16 bits in place (coalesced).
__global__ __launch_bounds__(256) void k_coef(const int* __restrict__ ptr,
                                              u32* __restrict__ epack,
                                              const float* __restrict__ dinv, int n) {
  int i = blockIdx.x * 256 + threadIdx.x;
  if (i >= n) return;
  float dc = dinv[i];
  int j = ptr[i], end = ptr[i + 1];
  for (; j < end; ++j) {
    u32 m = epack[j];
    float c = dinv[m >> 16] * __uint_as_float(m << 16) * dc;
    epack[j] = (m & 0xFFFF0000u) | (u32)f2bf(c);
  }
}

// ---------------- W pre-pack: fp32 row-major -> swizzled bf16 u64 cells ----
__global__ __launch_bounds__(256) void k_wpack(const float* __restrict__ W0,
                                               const float* __restrict__ W1,
                                               const float* __restrict__ W2,
                                               u64* __restrict__ cells) {
  const float* W = (blockIdx.x == 0) ? W0 : (blockIdx.x == 1) ? W1 : W2;
  u64* out = cells + (size_t)blockIdx.x * 4096;
  int t = threadIdx.x;
#pragma unroll
  for (int i = 0; i < 16; ++i) {
    int cell = t + 256 * i;        // 0..4095
    int col = cell >> 5;
    int k4 = cell & 31;
    int k = k4 * 4;
    u64 c = (u64)f2bf(W[(size_t)(k + 0) * 128 + col]) |
            ((u64)f2bf(W[(size_t)(k + 1) * 128 + col]) << 16) |
            ((u64)f2bf(W[(size_t)(k + 2) * 128 + col]) << 32) |
            ((u64)f2bf(W[(size_t)(k + 3) * 128 + col]) << 48);
    out[col * 32 + (k4 ^ (col & 15))] = c;
  }
}

// ---------------- bf16 MFMA GEMM -------------------------------------------
// C[n x 128](bf16) = act(A)[n x 128] * W[128 x 128].
// act = relu(v*A+B) with (A,B)=ab (prev layer's folded BN affine), or
// identity for layer 0. Blocks 0..15 zero this layer's 64-replica stats.
// W arrives pre-packed/swizzled; staging is a pure 32KB copy. LDS cells:
// 8B (4 bf16 along k) at [r*32 + (k4 ^ (r&15))]. C/D: col=lane&15,
// row=(lane>>4)*4+reg (m89-verified).
__global__ __launch_bounds__(256) void k_gemm(const void* __restrict__ Ain,
                                              int a_is_f32,
                                              const u64* __restrict__ Wc,
                                              u16* __restrict__ C,
                                              const float* __restrict__ ab,
                                              float* __restrict__ Szero,
                                              int n) {
  __shared__ u64 As64[128 * 32];   // 32 KB
  __shared__ u64 Ws64[128 * 32];   // 32 KB
  __shared__ float absh[256];      // folded BN affine A,B
  int t = threadIdx.x;
  if (blockIdx.x < 16) {           // zero this layer's 64-replica stats
#pragma unroll
    for (int i = 0; i < 4; ++i)
      Szero[blockIdx.x * 1024 + t + 256 * i] = 0.f;
  }
  {  // stage pre-packed W: pure copy, 16B vectors
    const ulonglong2* src = (const ulonglong2*)Wc;
    ulonglong2* dst = (ulonglong2*)Ws64;
#pragma unroll
    for (int i = 0; i < 8; ++i) dst[t + 256 * i] = src[t + 256 * i];
  }
  if (ab) {
    if (t < 128) {
      absh[t] = ab[t];
      absh[128 + t] = ab[128 + t];
    }
  }

  int row0 = blockIdx.x * 128;
  int nr = min(128, n - row0);

  if (a_is_f32) {                  // layer 0: fp32 input, no affine
    const float4* src = (const float4*)((const float*)Ain + (size_t)row0 * 128);
#pragma unroll
    for (int i = 0; i < 16; ++i) {
      int idx = t + 256 * i;       // float4 id within tile
      int r = idx >> 5;
      int j4 = idx & 31;           // cell k4 = j4
      float4 v = (r < nr) ? src[idx] : make_float4(0.f, 0.f, 0.f, 0.f);
      u64 cell = (u64)f2bf(v.x) | ((u64)f2bf(v.y) << 16) |
                 ((u64)f2bf(v.z) << 32) | ((u64)f2bf(v.w) << 48);
      As64[r * 32 + (j4 ^ (r & 15))] = cell;
    }
  } else {                         // bf16 input (+ optional affine+relu)
    const u16* A = (const u16*)Ain;
    __syncthreads();               // absh visible
#pragma unroll
    for (int i = 0; i < 8; ++i) {
      int idx = t + 256 * i;       // 16B chunk id
      int r = idx >> 4;
      int c8 = idx & 15;           // 8-bf16 chunk
      u64 lo = 0, hi = 0;
      if (r < nr) {
        const u64* srcq = (const u64*)(A + ((size_t)(row0 + r)) * 128 + c8 * 8);
        lo = srcq[0]; hi = srcq[1];
        if (ab) {
          u64 nl = 0, nh = 0;
#pragma unroll
          for (int j = 0; j < 4; ++j) {
            int c = c8 * 8 + j;
            float f = fmaxf(fmaf(bf2f((u16)(lo >> (16 * j))), absh[c], absh[128 + c]), 0.f);
            nl |= ((u64)f2bf(f)) << (16 * j);
            int c2 = c + 4;
            float f2 = fmaxf(fmaf(bf2f((u16)(hi >> (16 * j))), absh[c2], absh[128 + c2]), 0.f);
            nh |= ((u64)f2bf(f2)) << (16 * j);
          }
          lo = nl; hi = nh;
        }
      }
      As64[r * 32 + ((c8 * 2) ^ (r & 15))] = lo;
      As64[r * 32 + ((c8 * 2 + 1) ^ (r & 15))] = hi;
    }
  }
  __syncthreads();

  int w = t >> 6, l = t & 63;
  int lr = l & 15, kg = l >> 4;
  int rA0 = w * 32 + lr, rA1 = rA0 + 16;   // rA&15 == lr
  f32x4 acc[2][8];
#pragma unroll
  for (int m = 0; m < 2; ++m)
#pragma unroll
    for (int nf = 0; nf < 8; ++nf) acc[m][nf] = (f32x4){0.f, 0.f, 0.f, 0.f};

  union Frag { u64 q[2]; bf16x8 v; };
#pragma unroll
  for (int ks = 0; ks < 4; ++ks) {
    int kb = ks * 8 + kg;
    Frag a0, a1;
    a0.q[0] = As64[rA0 * 32 + (kb ^ lr)];
    a0.q[1] = As64[rA0 * 32 + ((kb + 4) ^ lr)];
    a1.q[0] = As64[rA1 * 32 + (kb ^ lr)];
    a1.q[1] = As64[rA1 * 32 + ((kb + 4) ^ lr)];
#pragma unroll
    for (int nf = 0; nf < 8; ++nf) {
      Frag b;
      b.q[0] = Ws64[(nf * 16 + lr) * 32 + (kb ^ lr)];
      b.q[1] = Ws64[(nf * 16 + lr) * 32 + ((kb + 4) ^ lr)];
      acc[0][nf] = __builtin_amdgcn_mfma_f32_16x16x32_bf16(a0.v, b.v, acc[0][nf], 0, 0, 0);
      acc[1][nf] = __builtin_amdgcn_mfma_f32_16x16x32_bf16(a1.v, b.v, acc[1][nf], 0, 0, 0);
    }
  }
#pragma unroll
  for (int m = 0; m < 2; ++m)
#pragma unroll
    for (int nf = 0; nf < 8; ++nf)
#pragma unroll
      for (int j = 0; j < 4; ++j) {
        int gr = row0 + w * 32 + m * 16 + kg * 4 + j;
        if (gr < n) C[(size_t)gr * 128 + nf * 16 + lr] = f2bf(acc[m][nf][j]);
      }
}

// ---------------- bf16 pull-gather + fused BN stats ------------------------
// Full 256B row per edge (one wave, 64x u32 lanes). Block covers 16 nodes
// (4 iters x 4 waves); register stats, one flush per block into replica
// (blockIdx&63). 4-edge unrolled, dual accumulators, u32 edge meta.
__global__ __launch_bounds__(256) void k_gather(const u16* __restrict__ hw,
                                                const int* __restrict__ ptr,
                                                const u32* __restrict__ epack,
                                                const float* __restrict__ dinv,
                                                u16* __restrict__ out,
                                                float* __restrict__ stats, int n) {
  int w = threadIdx.x >> 6;
  int lane4 = (threadIdx.x & 63) * 4;   // byte offset of lane's u32
  const char* hwb = (const char*)hw;
  float sx = 0.f, sy = 0.f, sxx = 0.f, syy = 0.f;
#pragma unroll
  for (int it = 0; it < 4; ++it) {
    int node = blockIdx.x * 16 + it * 4 + w;
    if (node < n) {
      float di = dinv[node];
      u32 su = *(const u32*)(hwb + ((size_t)node << 8) + lane4);
      float ax0 = __uint_as_float(su << 16) * di * di;
      float ay0 = __uint_as_float(su & 0xFFFF0000u) * di * di;
      float ax1 = 0.f, ay1 = 0.f;
      int j = ptr[node], end = ptr[node + 1];
      for (; j + 3 < end; j += 4) {
        u32 m0 = epack[j], m1 = epack[j + 1], m2 = epack[j + 2], m3 = epack[j + 3];
        float c0 = __uint_as_float(m0 << 16), c1 = __uint_as_float(m1 << 16);
        float c2 = __uint_as_float(m2 << 16), c3 = __uint_as_float(m3 << 16);
        u32 v0 = *(const u32*)(hwb + ((m0 & 0xFFFF0000u) >> 8) + lane4);
        u32 v1 = *(const u32*)(hwb + ((m1 & 0xFFFF0000u) >> 8) + lane4);
        u32 v2 = *(const u32*)(hwb + ((m2 & 0xFFFF0000u) >> 8) + lane4);
        u32 v3 = *(const u32*)(hwb + ((m3 & 0xFFFF0000u) >> 8) + lane4);
        ax0 = fmaf(__uint_as_float(v0 << 16), c0, ax0);
        ay0 = fmaf(__uint_as_float(v0 & 0xFFFF0000u), c0, ay0);
        ax1 = fmaf(__uint_as_float(v1 << 16), c1, ax1);
        ay1 = fmaf(__uint_as_float(v1 & 0xFFFF0000u), c1, ay1);
        ax0 = fmaf(__uint_as_float(v2 << 16), c2, ax0);
        ay0 = fmaf(__uint_as_float(v2 & 0xFFFF0000u), c2, ay0);
        ax1 = fmaf(__uint_as_float(v3 << 16), c3, ax1);
        ay1 = fmaf(__uint_as_float(v3 & 0xFFFF0000u), c3, ay1);
      }
      for (; j < end; ++j) {
        u32 m0 = epack[j];
        float c0 = __uint_as_float(m0 << 16);
        u32 v0 = *(const u32*)(hwb + ((m0 & 0xFFFF0000u) >> 8) + lane4);
        ax0 = fmaf(__uint_as_float(v0 << 16), c0, ax0);
        ay0 = fmaf(__uint_as_float(v0 & 0xFFFF0000u), c0, ay0);
      }
      float ax = ax0 + ax1, ay = ay0 + ay1;
      u32 o = (u32)f2bf(ax) | ((u32)f2bf(ay) << 16);
      *(u32*)((char*)out + ((size_t)node << 8) + lane4) = o;
      sx += ax; sy += ay;
      sxx = fmaf(ax, ax, sxx); syy = fmaf(ay, ay, syy);
    }
  }
  __shared__ float4 red[256];
  red[threadIdx.x] = make_float4(sx, sy, sxx, syy);
  __syncthreads();
  if (threadIdx.x < 64) {
    int t = threadIdx.x;
    float4 a = red[t], b = red[t + 64], c = red[t + 128], d = red[t + 192];
    float* S = stats + (blockIdx.x & (NREP - 1)) * 256;
    unsafeAtomicAdd(&S[2 * t],           a.x + b.x + c.x + d.x);
    unsafeAtomicAdd(&S[2 * t + 1],       a.y + b.y + c.y + d.y);
    unsafeAtomicAdd(&S[128 + 2 * t],     a.z + b.z + c.z + d.z);
    unsafeAtomicAdd(&S[128 + 2 * t + 1], a.w + b.w + c.w + d.w);
  }
}

// ---------------- BN finalize: reduce replicas -> folded affine ------------
__global__ __launch_bounds__(128) void k_bn_finalize(const float* __restrict__ S,
                                                     const float* __restrict__ g,
                                                     const float* __restrict__ be,
                                                     float* __restrict__ ab, int n) {
  int c = threadIdx.x;
  float s = 0.f, ss = 0.f;
#pragma unroll 8
  for (int r = 0; r < NREP; ++r) {
    s += S[r * 256 + c];
    ss += S[r * 256 + 128 + c];
  }
  float inv_n = 1.0f / (float)n;
  float mu = s * inv_n;
  float var = ss * inv_n - mu * mu;
  float istd = rsqrtf(var + 1e-5f);
  float A = g[c] * istd;
  ab[c] = A;
  ab[128 + c] = fmaf(-mu, A, be[c]);
}

// ---------------- head -----------------------------------------------------
__global__ __launch_bounds__(256) void k_head(const u16* __restrict__ h,
                                              const float* __restrict__ ab,
                                              const float* __restrict__ Wh,
                                              const float* __restrict__ bh,
                                              const float* __restrict__ Wa,
                                              const float* __restrict__ ba,
                                              const float* __restrict__ Wz,
                                              const float* __restrict__ bz,
                                              float* __restrict__ out) {
  __shared__ float hrow[256];
  __shared__ float red[256];
  int t = threadIdx.x;
  {
    int c = t & 127;
    hrow[t] = fmaxf(fmaf(bf2f(h[t]), ab[c], ab[128 + c]), 0.f);
  }
  __syncthreads();
  int j = t & 127, r = t >> 7;
  float acc = bh[j];
  for (int k = 0; k < 128; ++k)
    acc = fmaf(hrow[r * 128 + k], Wh[k * 128 + j], acc);
  float hv = fmaxf(acc, 0.f);
  float wv = (r == 0) ? Wa[j] : Wz[j];
  red[t] = hv * wv;
  __syncthreads();
  for (int s = 64; s >= 1; s >>= 1) {
    if (j < s) red[t] += red[t + s];
    __syncthreads();
  }
  if (t == 0) out[0] = red[0] + ba[0];
  if (t == 128) out[1] = red[128] + bz[0];
}

extern "C" void kernel_launch(void* const* d_in, const int* in_sizes, int n_in,
                              void* d_out, int out_size, void* d_ws, size_t ws_size,
                              hipStream_t stream) {
  const float* x  = (const float*)d_in[0];
  const int*   ei = (const int*)d_in[1];
  const float* ew = (const float*)d_in[2];
  const float* W[3]  = {(const float*)d_in[3], (const float*)d_in[5], (const float*)d_in[7]};
  // b1/b2/b3 cancel inside BatchNorm -> skipped.
  const float* g[3]  = {(const float*)d_in[9],  (const float*)d_in[11], (const float*)d_in[13]};
  const float* be[3] = {(const float*)d_in[10], (const float*)d_in[12], (const float*)d_in[14]};
  const float* Wh = (const float*)d_in[15];
  const float* bh = (const float*)d_in[16];
  const float* Wa = (const float*)d_in[17];
  const float* ba = (const float*)d_in[18];
  const float* Wz = (const float*)d_in[19];
  const float* bz = (const float*)d_in[20];

  const int n = in_sizes[0] / 128;
  const int e = in_sizes[1] / 2;
  const int* row = ei;
  const int* col = ei + e;

  u16*   hw_b   = (u16*)d_ws;
  u16*   hbuf_b = hw_b + (size_t)n * 128;
  float* dinv   = (float*)(hbuf_b + (size_t)n * 128);
  float* stats3 = dinv + n;                 // 3 * NREP * 256
  float* ab     = stats3 + 3 * NREP * 256;  // 3 * 256
  u64*   wcells = (u64*)(ab + 3 * 256);     // 3 * 4096
  int*   cnt    = (int*)(wcells + 3 * 4096);
  int*   ptr    = cnt + n;
  int*   bsum   = ptr + n + 1;              // 256
  int*   rank   = bsum + 256;               // E
  u32*   epack  = (u32*)(rank + e);         // E

  const int nb_n = (n + 255) / 256;
  const int nb_e = (e + 255) / 256;

  hipMemsetAsync(cnt, 0, (size_t)n * sizeof(int), stream);
  k_count_rank<<<nb_e, 256, 0, stream>>>(col, cnt, rank, e);
  k_scan1<<<nb_n, 256, 0, stream>>>(cnt, ptr, bsum, n);
  k_scan2<<<1, 256, 0, stream>>>(bsum, nb_n);
  k_scan3<<<nb_n, 256, 0, stream>>>(ptr, bsum, n, e);
  k_fill<<<nb_e, 256, 0, stream>>>(row, col, ew, ptr, rank, epack, e);
  k_deg_dinv<<<nb_n, 256, 0, stream>>>(ptr, epack, dinv, n);
  k_coef<<<nb_n, 256, 0, stream>>>(ptr, epack, dinv, n);
  k_wpack<<<3, 256, 0, stream>>>(W[0], W[1], W[2], wcells);

  for (int l = 0; l < 3; ++l) {
    const void* hin = (l == 0) ? (const void*)x : (const void*)hbuf_b;
    const float* abp = (l == 0) ? nullptr : (ab + (l - 1) * 256);
    k_gemm<<<(n + 127) / 128, 256, 0, stream>>>(hin, (l == 0) ? 1 : 0,
                                                wcells + (size_t)l * 4096,
                                                hw_b, abp,
                                                stats3 + l * NREP * 256, n);
    k_gather<<<(n + 15) / 16, 256, 0, stream>>>(hw_b, ptr, epack, dinv, hbuf_b,
                                                stats3 + l * NREP * 256, n);
    k_bn_finalize<<<1, 128, 0, stream>>>(stats3 + l * NREP * 256, g[l], be[l],
                                         ab + l * 256, n);
  }
  k_head<<<1, 256, 0, stream>>>(hbuf_b, ab + 2 * 256, Wh, bh, Wa, ba, Wz, bz,
                                (float*)d_out);
}